// Round 13
// baseline (1098.317 us; speedup 1.0000x reference)
//
#include <hip/hip_runtime.h>

#define N_NODES 50000
#define BDIM 8
#define DDIM 64
#define ODIM 64
#define KM 5
#define BD 512          // B*D
#define CAP 72          // bucket capacity per row (deg ~ Poisson(32), max ~58)
#define CAPL 76         // LDS row stride for cv (u32)
#define YSTR 88         // LDS row stride for y-tile (u16)
#define SCHUNKS 8
#define CROWS (N_NODES / SCHUNKS)
#define SFEAT 64        // hop2 slice width (row-major slabs)
#define SF32 32         // era slice width (slice-major x0)
#define NERA 16
#define RBLK_H ((N_NODES + 31) / 32)  // 1563 row-blocks (32 rows each)

typedef unsigned int u32;
typedef unsigned short u16;
typedef unsigned long long u64;

typedef __attribute__((ext_vector_type(8))) short short8;
typedef __attribute__((ext_vector_type(4))) float f32x4;
typedef __attribute__((ext_vector_type(4))) unsigned int u32x4;

__device__ __forceinline__ u16 pack1(float f) {
  u32 a = __float_as_uint(f);
  return (u16)((a + 0x7FFFu + ((a >> 16) & 1u)) >> 16);
}
__device__ __forceinline__ u32 pack2(float f0, float f1) {
  return (u32)pack1(f0) | ((u32)pack1(f1) << 16);
}
__device__ __forceinline__ float bfl(u32 u) { return __uint_as_float(u << 16); }
__device__ __forceinline__ float bfh(u32 u) { return __uint_as_float(u & 0xFFFF0000u); }

__device__ __forceinline__ int wave_max(int v) {
  v = max(v, __shfl_xor(v, 8));
  v = max(v, __shfl_xor(v, 16));
  v = max(v, __shfl_xor(v, 32));
  return v;
}

// ---------------- transpose: x (B,N,D) fp32 -> x0sl [era][n][32] bf16 (slice-major) ----------------
__global__ void k_transpose_h(const float* __restrict__ x, u16* __restrict__ x0sl, int tot4) {
  int i = blockIdx.x * blockDim.x + threadIdx.x;
  if (i >= tot4) return;
  int f = i << 2;
  int d = f & (DDIM - 1);
  int nb = f >> 6;                // b*N + n
  int b = nb / N_NODES;
  int n = nb - b * N_NODES;
  int s = b * 2 + (d >> 5);
  int fo = d & 31;
  float4 v = *(const float4*)(x + (size_t)f);
  uint2 w = make_uint2(pack2(v.x, v.y), pack2(v.z, v.w));
  *(uint2*)(x0sl + ((size_t)s * N_NODES + n) * SF32 + fo) = w;
}

// ---------------- chunked one-pass scatter into fixed-capacity row buckets ----------------
__global__ void __launch_bounds__(256) k_scatter_cap(
    const int* __restrict__ r0, const int* __restrict__ c0, const float* __restrict__ v0,
    const int* __restrict__ r1, const int* __restrict__ c1, const float* __restrict__ v1,
    int* __restrict__ cnt /*2N*/, u32* __restrict__ cv /*2N*CAP*/, int E4, int bpc) {
  int chunk = blockIdx.x / bpc;
  int i = (blockIdx.x - chunk * bpc) * blockDim.x + threadIdx.x;
  int lo = chunk * CROWS;
  const int* rr; const int* cc; const float* vv; int base, j;
  if (i < E4) { rr = r0; cc = c0; vv = v0; base = 0; j = i; }
  else if (i < 2 * E4) { rr = r1; cc = c1; vv = v1; base = N_NODES; j = i - E4; }
  else return;
  int4 r = *(const int4*)(rr + (size_t)j * 4);
  int4 c = *(const int4*)(cc + (size_t)j * 4);
  float4 v = *(const float4*)(vv + (size_t)j * 4);
  int p;
  if ((u32)(r.x - lo) < CROWS) {
    p = atomicAdd(&cnt[base + r.x], 1);
    if (p < CAP) cv[(size_t)(base + r.x) * CAP + p] = (u32)c.x | ((u32)pack1(v.x) << 16);
  }
  if ((u32)(r.y - lo) < CROWS) {
    p = atomicAdd(&cnt[base + r.y], 1);
    if (p < CAP) cv[(size_t)(base + r.y) * CAP + p] = (u32)c.y | ((u32)pack1(v.y) << 16);
  }
  if ((u32)(r.z - lo) < CROWS) {
    p = atomicAdd(&cnt[base + r.z], 1);
    if (p < CAP) cv[(size_t)(base + r.z) * CAP + p] = (u32)c.z | ((u32)pack1(v.z) << 16);
  }
  if ((u32)(r.w - lo) < CROWS) {
    p = atomicAdd(&cnt[base + r.w], 1);
    if (p < CAP) cv[(size_t)(base + r.w) * CAP + p] = (u32)c.w | ((u32)pack1(v.w) << 16);
  }
}

// ---------------- weight reorder: wfrag[((k*2+h)*4+ob)*64+lane][j] bf16 ----------------
__global__ void k_prep_w(const float* __restrict__ weight, u16* __restrict__ wfrag) {
  for (int i = threadIdx.x; i < 2560; i += 256) {
    int lane = i & 63;
    int ob = (i >> 6) & 3;
    int half = (i >> 8) & 1;
    int k = i >> 9;
    int o = ob * 16 + (lane & 15);
    #pragma unroll
    for (int j = 0; j < 8; ++j) {
      int d = half * 32 + ((lane >> 4) * 8) + j;
      wfrag[(size_t)i * 8 + j] = pack1(weight[(d * KM + k) * ODIM + o]);
    }
  }
}

__device__ __forceinline__ const short8* wfp(const u16* __restrict__ wfrag,
                                             int k, int h, int ob, int lane) {
  return (const short8*)(wfrag + (size_t)((((k * 2 + h) * 4 + ob) * 64 + lane) * 8));
}

// ---------------- gather helpers ----------------
__device__ __forceinline__ void fma8(float a[8], uint4 q, float v) {
  a[0] = fmaf(v, bfl(q.x), a[0]); a[1] = fmaf(v, bfh(q.x), a[1]);
  a[2] = fmaf(v, bfl(q.y), a[2]); a[3] = fmaf(v, bfh(q.y), a[3]);
  a[4] = fmaf(v, bfl(q.z), a[4]); a[5] = fmaf(v, bfh(q.z), a[5]);
  a[6] = fmaf(v, bfl(q.w), a[6]); a[7] = fmaf(v, bfh(q.w), a[7]);
}

// row-major source, stride BD, uint4 (8 feats/lane)
__device__ __forceinline__ void gather_lds(const u32* __restrict__ cvp /*LDS*/,
                                           const u16* __restrict__ xb,
                                           int n, int nmax, float acc[8]) {
  float A0[8] = {}, A1[8] = {}, A2[8] = {}, A3[8] = {};
  int e = 0;
  for (; e + 4 <= nmax; e += 4) {
    uint4 q = *(const uint4*)(cvp + e);
    u32 q0 = (e + 0 < n) ? q.x : 0u;
    u32 q1 = (e + 1 < n) ? q.y : 0u;
    u32 q2 = (e + 2 < n) ? q.z : 0u;
    u32 q3 = (e + 3 < n) ? q.w : 0u;
    uint4 d0 = *(const uint4*)(xb + (size_t)(q0 & 0xFFFFu) * BD);
    uint4 d1 = *(const uint4*)(xb + (size_t)(q1 & 0xFFFFu) * BD);
    uint4 d2 = *(const uint4*)(xb + (size_t)(q2 & 0xFFFFu) * BD);
    uint4 d3 = *(const uint4*)(xb + (size_t)(q3 & 0xFFFFu) * BD);
    fma8(A0, d0, bfh(q0));
    fma8(A1, d1, bfh(q1));
    fma8(A2, d2, bfh(q2));
    fma8(A3, d3, bfh(q3));
  }
  for (; e < nmax; ++e) {
    u32 q = (e < n) ? cvp[e] : 0u;
    uint4 d = *(const uint4*)(xb + (size_t)(q & 0xFFFFu) * BD);
    fma8(A0, d, bfh(q));
  }
  #pragma unroll
  for (int j = 0; j < 8; ++j) acc[j] = (A0[j] + A1[j]) + (A2[j] + A3[j]);
}

// slice-major source, stride SF32, uint2 (4 feats/lane)
__device__ __forceinline__ void fma4(float a[4], uint2 q, float v) {
  a[0] = fmaf(v, bfl(q.x), a[0]); a[1] = fmaf(v, bfh(q.x), a[1]);
  a[2] = fmaf(v, bfl(q.y), a[2]); a[3] = fmaf(v, bfh(q.y), a[3]);
}

__device__ __forceinline__ void gather4(const u32* __restrict__ cvp /*LDS*/,
                                        const u16* __restrict__ xb,
                                        int n, int nmax, float acc[4]) {
  float A0[4] = {}, A1[4] = {}, A2[4] = {}, A3[4] = {};
  for (int e = 0; e < nmax; e += 4) {
    uint4 q = *(const uint4*)(cvp + e);
    u32 q0 = (e + 0 < n) ? q.x : 0u;
    u32 q1 = (e + 1 < n) ? q.y : 0u;
    u32 q2 = (e + 2 < n) ? q.z : 0u;
    u32 q3 = (e + 3 < n) ? q.w : 0u;
    uint2 d0 = *(const uint2*)(xb + (size_t)(q0 & 0xFFFFu) * SF32);
    uint2 d1 = *(const uint2*)(xb + (size_t)(q1 & 0xFFFFu) * SF32);
    uint2 d2 = *(const uint2*)(xb + (size_t)(q2 & 0xFFFFu) * SF32);
    uint2 d3 = *(const uint2*)(xb + (size_t)(q3 & 0xFFFFu) * SF32);
    fma4(A0, d0, bfh(q0));
    fma4(A1, d1, bfh(q1));
    fma4(A2, d2, bfh(q2));
    fma4(A3, d3, bfh(q3));
  }
  #pragma unroll
  for (int j = 0; j < 4; ++j) acc[j] = (A0[j] + A1[j]) + (A2[j] + A3[j]);
}

// ---------------- stage G graphs' buckets (trimmed to actual degree) into LDS ----------------
template<int G>
__device__ __forceinline__ void stage_cv(const int* __restrict__ cnt, const u32* __restrict__ cv,
                                         int rbase, u32* __restrict__ cvl, int* __restrict__ nn) {
  if (threadIdx.x < 32 * G) {
    int g = threadIdx.x >> 5, i2 = threadIdx.x & 31;
    int node = rbase + i2;
    nn[threadIdx.x] = (node < N_NODES) ? min(cnt[g * N_NODES + node], CAP) : 0;
  }
  __syncthreads();
  const int QR = CAP / 4;   // 18 uint4 per row
  for (int idx = threadIdx.x; idx < G * 32 * QR; idx += 256) {
    int g = idx / (32 * QR);
    int rem = idx - g * (32 * QR);
    int i2 = rem / QR, w = rem - i2 * QR;
    if (w * 4 < nn[g * 32 + i2]) {      // trimmed: only live entries
      int node = rbase + i2;
      u32x4 q = __builtin_nontemporal_load(
          (const u32x4*)(cv + (size_t)(g * N_NODES + node) * CAP + w * 4));
      *(u32x4*)(&cvl[(g * 32 + i2) * CAPL + w * 4]) = q;
    }
  }
  __syncthreads();
}

// ---------------- per-era gather (launch = era sync): both graphs, one 32-feat slice ----------------
// reads x0sl era block (3.2MB, L2-resident chip-wide), writes slabs ROW-major
__global__ void __launch_bounds__(256, 8) k_gath_era(const int* __restrict__ cnt,
                                                     const u32* __restrict__ cv,
                                                     const u16* __restrict__ x0sl,
                                                     u16* __restrict__ slabA0,
                                                     u16* __restrict__ slabA1,
                                                     int s) {
  __shared__ u32 cvl[2 * 32 * CAPL];
  __shared__ int nn[64];
  const int rbase = blockIdx.x * 32;
  stage_cv<2>(cnt, cv, rbase, cvl, nn);

  const int wid = threadIdx.x >> 6, lane = threadIdx.x & 63;
  const int gi = lane >> 3, pe = lane & 7;
  const int i2 = wid * 8 + gi;
  const int node = rbase + i2;
  const int n0 = nn[i2], n1 = nn[32 + i2];
  const int m0 = wave_max(n0), m1 = wave_max(n1);
  const u32* cvp0 = &cvl[i2 * CAPL];
  const u32* cvp1 = &cvl[(32 + i2) * CAPL];

  const u16* xb = x0sl + (size_t)s * N_NODES * SF32 + pe * 4;
  float y0[4], y1[4];
  gather4(cvp0, xb, n0, m0, y0);
  gather4(cvp1, xb, n1, m1, y1);
  if (node < N_NODES) {
    size_t doff = (size_t)node * BD + s * SF32 + pe * 4;   // row-major slab
    u64 s0 = (u64)pack2(y0[0], y0[1]) | ((u64)pack2(y0[2], y0[3]) << 32);
    u64 s1 = (u64)pack2(y1[0], y1[1]) | ((u64)pack2(y1[2], y1[3]) << 32);
    __builtin_nontemporal_store(s0, (u64*)(slabA0 + doff));
    __builtin_nontemporal_store(s1, (u64*)(slabA1 + doff));
  }
}

// ---------------- hop2: y = 2*(A@slab) - x0; out (=/+=) [k0] + slab@W_KSELF + y@W_KY ----------------
// grid = 2*RBLK_H: sid handles slices [sid*4, sid*4+4). FIRST: also k0 term + bias, plain write.
template<int KSELF, int KY, bool FIRST>
__global__ void __launch_bounds__(256, 4) k_hop2(const int* __restrict__ cnt_g,
                                                 const u32* __restrict__ cv_g,
                                                 const u16* __restrict__ srcslab,
                                                 const u16* __restrict__ x0sl,
                                                 const u16* __restrict__ wfrag,
                                                 const float* __restrict__ bias,
                                                 float* __restrict__ out) {
  __shared__ u32 cvl[32 * CAPL];
  __shared__ int nn[32];
  __shared__ u16 ytile[32 * YSTR];
  const int sid = blockIdx.x / RBLK_H;
  const int rbase = (blockIdx.x - sid * RBLK_H) * 32;
  stage_cv<1>(cnt_g, cv_g, rbase, cvl, nn);

  const int wid = threadIdx.x >> 6, lane = threadIdx.x & 63;
  const int gi = lane >> 3, pe = lane & 7;
  const int i2 = wid * 8 + gi;
  const int node = rbase + i2;
  const int nsafe = min(node, N_NODES - 1);
  const int n = nn[i2];
  const int m = wave_max(n);
  const u32* cvp = &cvl[i2 * CAPL];

  const int t = wid >> 1, obp = (wid & 1) * 2;
  const int ar = lane & 15, kg = lane >> 4, col = lane & 15;
  const int anode = min(rbase + t * 16 + ar, N_NODES - 1);
  const float bv0 = bias[obp * 16 + col];
  const float bv1 = bias[(obp + 1) * 16 + col];

  // cheb read position in slice-major x0sl for this lane's 8 feats
  const int ec_h = pe >> 2;           // which era of the pair
  const int ec_off = (pe & 3) * 8;    // feat offset within era

  for (int s = sid * 4; s < sid * 4 + 4; ++s) {
    const u16* xb = srcslab + s * SFEAT + pe * 8;   // row-major slab gather
    float y[8];
    gather_lds(cvp, xb, n, m, y);
    {
      uint4 qp = *(const uint4*)(x0sl + ((size_t)(2 * s + ec_h) * N_NODES + nsafe) * SF32 + ec_off);
      float p[8] = {bfl(qp.x), bfh(qp.x), bfl(qp.y), bfh(qp.y),
                    bfl(qp.z), bfh(qp.z), bfl(qp.w), bfh(qp.w)};
      #pragma unroll
      for (int j = 0; j < 8; ++j) y[j] = 2.f * y[j] - p[j];
    }
    *(uint4*)(&ytile[i2 * YSTR + pe * 8]) =
        make_uint4(pack2(y[0], y[1]), pack2(y[2], y[3]),
                   pack2(y[4], y[5]), pack2(y[6], y[7]));
    __syncthreads();
    f32x4 acc0 = {0.f, 0.f, 0.f, 0.f}, acc1 = {0.f, 0.f, 0.f, 0.f};
    #pragma unroll
    for (int h = 0; h < 2; ++h) {
      short8 aS = *(const short8*)(srcslab + (size_t)anode * BD + s * SFEAT + h * 32 + kg * 8);
      short8 aY = *(const short8*)(&ytile[(t * 16 + ar) * YSTR + h * 32 + kg * 8]);
      acc0 = __builtin_amdgcn_mfma_f32_16x16x32_bf16(aS, *wfp(wfrag, KSELF, h, obp, lane), acc0, 0, 0, 0);
      acc1 = __builtin_amdgcn_mfma_f32_16x16x32_bf16(aS, *wfp(wfrag, KSELF, h, obp + 1, lane), acc1, 0, 0, 0);
      acc0 = __builtin_amdgcn_mfma_f32_16x16x32_bf16(aY, *wfp(wfrag, KY, h, obp, lane), acc0, 0, 0, 0);
      acc1 = __builtin_amdgcn_mfma_f32_16x16x32_bf16(aY, *wfp(wfrag, KY, h, obp + 1, lane), acc1, 0, 0, 0);
      if (FIRST) {
        short8 a0f = *(const short8*)(x0sl + ((size_t)(2 * s + h) * N_NODES + anode) * SF32 + kg * 8);
        acc0 = __builtin_amdgcn_mfma_f32_16x16x32_bf16(a0f, *wfp(wfrag, 0, h, obp, lane), acc0, 0, 0, 0);
        acc1 = __builtin_amdgcn_mfma_f32_16x16x32_bf16(a0f, *wfp(wfrag, 0, h, obp + 1, lane), acc1, 0, 0, 0);
      }
    }
    #pragma unroll
    for (int reg = 0; reg < 4; ++reg) {
      int onode = rbase + t * 16 + kg * 4 + reg;
      if (onode < N_NODES) {
        size_t ob_ = ((size_t)s * N_NODES + onode) * ODIM;
        if (FIRST) {
          out[ob_ + obp * 16 + col] = acc0[reg] + bv0;
          out[ob_ + (obp + 1) * 16 + col] = acc1[reg] + bv1;
        } else {
          out[ob_ + obp * 16 + col] += acc0[reg];
          out[ob_ + (obp + 1) * 16 + col] += acc1[reg];
        }
      }
    }
    __syncthreads();   // ytile reused next slice
  }
}

// ---------------- launcher ----------------
extern "C" void kernel_launch(void* const* d_in, const int* in_sizes, int n_in,
                              void* d_out, int out_size, void* d_ws, size_t ws_size,
                              hipStream_t stream) {
  const float* x      = (const float*)d_in[0];
  const int*   rows0  = (const int*)d_in[1];
  const int*   cols0  = (const int*)d_in[2];
  const float* vals0  = (const float*)d_in[3];
  const int*   rows1  = (const int*)d_in[4];
  const int*   cols1  = (const int*)d_in[5];
  const float* vals1  = (const float*)d_in[6];
  const float* weight = (const float*)d_in[7];
  const float* bias   = (const float*)d_in[8];
  float* out = (float*)d_out;
  const int E = in_sizes[1];
  const int E4 = E >> 2;

  char* p = (char*)d_ws;
  auto alloc = [&](size_t bytes) {
    char* q = p;
    p += (bytes + 255) & ~(size_t)255;
    return q;
  };
  u16* x0sl   = (u16*)alloc((size_t)N_NODES * BD * sizeof(u16));        // 51.2 MB
  u16* slabA0 = (u16*)alloc((size_t)N_NODES * BD * sizeof(u16));        // 51.2 MB
  u16* slabA1 = (u16*)alloc((size_t)N_NODES * BD * sizeof(u16));        // 51.2 MB
  int* cnt    = (int*)alloc((size_t)2 * N_NODES * sizeof(int));         // 0.4 MB
  u32* cv     = (u32*)alloc((size_t)2 * N_NODES * CAP * sizeof(u32));   // 28.8 MB
  u16* wfrag  = (u16*)alloc((size_t)2560 * 8 * sizeof(u16));            // 40 KB
  if ((size_t)(p - (char*)d_ws) > ws_size) return;

  const int tot4 = BDIM * N_NODES * DDIM / 4;
  k_transpose_h<<<(tot4 + 255) / 256, 256, 0, stream>>>(x, x0sl, tot4);

  (void)hipMemsetAsync(cnt, 0, (size_t)2 * N_NODES * sizeof(int), stream);
  const int bpc = (2 * E4 + 255) / 256;
  k_scatter_cap<<<SCHUNKS * bpc, 256, 0, stream>>>(rows0, cols0, vals0,
                                                   rows1, cols1, vals1,
                                                   cnt, cv, E4, bpc);
  k_prep_w<<<1, 256, 0, stream>>>(weight, wfrag);

  // hop 1: 16 era-synced launches (launch boundary = hard sync; era block = 3.2MB < 4MB L2)
  for (int s = 0; s < NERA; ++s)
    k_gath_era<<<RBLK_H, 256, 0, stream>>>(cnt, cv, x0sl, slabA0, slabA1, s);

  // hop 2 graph 0: out = bias + k0 + k1 + k2 (plain write)
  k_hop2<1, 2, true><<<2 * RBLK_H, 256, 0, stream>>>(cnt, cv, slabA0, x0sl, wfrag, bias, out);
  // hop 2 graph 1: out += k3 + k4
  k_hop2<3, 4, false><<<2 * RBLK_H, 256, 0, stream>>>(cnt + N_NODES, cv + (size_t)N_NODES * CAP,
                                                      slabA1, x0sl, wfrag, bias, out);
}

// Round 15
// 1062.986 us; speedup vs baseline: 1.0332x; 1.0332x over previous
//
#include <hip/hip_runtime.h>

#define N_NODES 50000
#define BDIM 8
#define DDIM 64
#define ODIM 64
#define KM 5
#define BD 512          // B*D
#define CAP 72          // bucket capacity per row (deg ~ Poisson(32), max ~58)
#define CAPL 76         // LDS row stride for cv (u32)
#define YSTR 88         // LDS row stride for y-tile (u16)
#define SCHUNKS 8
#define CROWS (N_NODES / SCHUNKS)
#define SLICES 8
#define SFEAT 64        // features per slice == one batch
#define RBLK_H ((N_NODES + 31) / 32)  // 1563 row-blocks (32 rows each)

typedef unsigned int u32;
typedef unsigned short u16;

typedef __attribute__((ext_vector_type(8))) short short8;
typedef __attribute__((ext_vector_type(4))) float f32x4;

__device__ __forceinline__ u16 pack1(float f) {
  u32 a = __float_as_uint(f);
  return (u16)((a + 0x7FFFu + ((a >> 16) & 1u)) >> 16);
}
__device__ __forceinline__ u32 pack2(float f0, float f1) {
  return (u32)pack1(f0) | ((u32)pack1(f1) << 16);
}
__device__ __forceinline__ float bfl(u32 u) { return __uint_as_float(u << 16); }
__device__ __forceinline__ float bfh(u32 u) { return __uint_as_float(u & 0xFFFF0000u); }

__device__ __forceinline__ int wave_max(int v) {
  v = max(v, __shfl_xor(v, 8));
  v = max(v, __shfl_xor(v, 16));
  v = max(v, __shfl_xor(v, 32));
  return v;
}

// ---------------- transpose: x (B,N,D) fp32 -> x0h (N, B*D) bf16 ----------------
__global__ void k_transpose_h(const float* __restrict__ x, u16* __restrict__ x0h, int tot4) {
  int i = blockIdx.x * blockDim.x + threadIdx.x;
  if (i >= tot4) return;
  int f = i << 2;
  int d = f & (DDIM - 1);
  int nb = f >> 6;                // b*N + n
  int b = nb / N_NODES;
  int n = nb - b * N_NODES;
  float4 v = *(const float4*)(x + (size_t)f);
  uint2 w = make_uint2(pack2(v.x, v.y), pack2(v.z, v.w));
  *(uint2*)(x0h + (size_t)n * BD + b * DDIM + d) = w;
}

// ---------------- chunked one-pass scatter into fixed-capacity row buckets ----------------
__global__ void __launch_bounds__(256) k_scatter_cap(
    const int* __restrict__ r0, const int* __restrict__ c0, const float* __restrict__ v0,
    const int* __restrict__ r1, const int* __restrict__ c1, const float* __restrict__ v1,
    int* __restrict__ cnt /*2N*/, u32* __restrict__ cv /*2N*CAP*/, int E4, int bpc) {
  int chunk = blockIdx.x / bpc;
  int i = (blockIdx.x - chunk * bpc) * blockDim.x + threadIdx.x;
  int lo = chunk * CROWS;
  const int* rr; const int* cc; const float* vv; int base, j;
  if (i < E4) { rr = r0; cc = c0; vv = v0; base = 0; j = i; }
  else if (i < 2 * E4) { rr = r1; cc = c1; vv = v1; base = N_NODES; j = i - E4; }
  else return;
  int4 r = *(const int4*)(rr + (size_t)j * 4);
  int4 c = *(const int4*)(cc + (size_t)j * 4);
  float4 v = *(const float4*)(vv + (size_t)j * 4);
  int p;
  if ((u32)(r.x - lo) < CROWS) {
    p = atomicAdd(&cnt[base + r.x], 1);
    if (p < CAP) cv[(size_t)(base + r.x) * CAP + p] = (u32)c.x | ((u32)pack1(v.x) << 16);
  }
  if ((u32)(r.y - lo) < CROWS) {
    p = atomicAdd(&cnt[base + r.y], 1);
    if (p < CAP) cv[(size_t)(base + r.y) * CAP + p] = (u32)c.y | ((u32)pack1(v.y) << 16);
  }
  if ((u32)(r.z - lo) < CROWS) {
    p = atomicAdd(&cnt[base + r.z], 1);
    if (p < CAP) cv[(size_t)(base + r.z) * CAP + p] = (u32)c.z | ((u32)pack1(v.z) << 16);
  }
  if ((u32)(r.w - lo) < CROWS) {
    p = atomicAdd(&cnt[base + r.w], 1);
    if (p < CAP) cv[(size_t)(base + r.w) * CAP + p] = (u32)c.w | ((u32)pack1(v.w) << 16);
  }
}

// ---------------- weight reorder: wfrag[((k*2+h)*4+ob)*64+lane][j] bf16 ----------------
__global__ void k_prep_w(const float* __restrict__ weight, u16* __restrict__ wfrag) {
  for (int i = threadIdx.x; i < 2560; i += 256) {
    int lane = i & 63;
    int ob = (i >> 6) & 3;
    int half = (i >> 8) & 1;
    int k = i >> 9;
    int o = ob * 16 + (lane & 15);
    #pragma unroll
    for (int j = 0; j < 8; ++j) {
      int d = half * 32 + ((lane >> 4) * 8) + j;
      wfrag[(size_t)i * 8 + j] = pack1(weight[(d * KM + k) * ODIM + o]);
    }
  }
}

__device__ __forceinline__ const short8* wfp(const u16* __restrict__ wfrag,
                                             int k, int h, int ob, int lane) {
  return (const short8*)(wfrag + (size_t)((((k * 2 + h) * 4 + ob) * 64 + lane) * 8));
}

// ---------------- gather 8 fp32 feats from LDS-staged edge list ----------------
__device__ __forceinline__ void fma8(float a[8], uint4 q, float v) {
  a[0] = fmaf(v, bfl(q.x), a[0]); a[1] = fmaf(v, bfh(q.x), a[1]);
  a[2] = fmaf(v, bfl(q.y), a[2]); a[3] = fmaf(v, bfh(q.y), a[3]);
  a[4] = fmaf(v, bfl(q.z), a[4]); a[5] = fmaf(v, bfh(q.z), a[5]);
  a[6] = fmaf(v, bfl(q.w), a[6]); a[7] = fmaf(v, bfh(q.w), a[7]);
}

__device__ __forceinline__ void gather_lds(const u32* __restrict__ cvp /*LDS*/,
                                           const u16* __restrict__ xb,
                                           int n, int nmax, float acc[8]) {
  float A0[8] = {}, A1[8] = {}, A2[8] = {}, A3[8] = {};
  int e = 0;
  for (; e + 4 <= nmax; e += 4) {
    uint4 q = *(const uint4*)(cvp + e);
    u32 q0 = (e + 0 < n) ? q.x : 0u;
    u32 q1 = (e + 1 < n) ? q.y : 0u;
    u32 q2 = (e + 2 < n) ? q.z : 0u;
    u32 q3 = (e + 3 < n) ? q.w : 0u;
    uint4 d0 = *(const uint4*)(xb + (size_t)(q0 & 0xFFFFu) * BD);
    uint4 d1 = *(const uint4*)(xb + (size_t)(q1 & 0xFFFFu) * BD);
    uint4 d2 = *(const uint4*)(xb + (size_t)(q2 & 0xFFFFu) * BD);
    uint4 d3 = *(const uint4*)(xb + (size_t)(q3 & 0xFFFFu) * BD);
    fma8(A0, d0, bfh(q0));
    fma8(A1, d1, bfh(q1));
    fma8(A2, d2, bfh(q2));
    fma8(A3, d3, bfh(q3));
  }
  for (; e < nmax; ++e) {
    u32 q = (e < n) ? cvp[e] : 0u;
    uint4 d = *(const uint4*)(xb + (size_t)(q & 0xFFFFu) * BD);
    fma8(A0, d, bfh(q));
  }
  #pragma unroll
  for (int j = 0; j < 8; ++j) acc[j] = (A0[j] + A1[j]) + (A2[j] + A3[j]);
}

// ---------------- stage G graphs' buckets for this block's 32 rows into LDS ----------------
template<int G>
__device__ __forceinline__ void stage_cv(const int* __restrict__ cnt, const u32* __restrict__ cv,
                                         int rbase, u32* __restrict__ cvl, int* __restrict__ nn) {
  if (threadIdx.x < 32 * G) {
    int g = threadIdx.x >> 5, i2 = threadIdx.x & 31;
    int node = rbase + i2;
    nn[threadIdx.x] = (node < N_NODES) ? min(cnt[g * N_NODES + node], CAP) : 0;
  }
  const int QR = CAP / 4;   // 18 uint4 per row
  for (int idx = threadIdx.x; idx < G * 32 * QR; idx += 256) {
    int g = idx / (32 * QR);
    int rem = idx - g * (32 * QR);
    int i2 = rem / QR, w = rem - i2 * QR;
    int node = rbase + i2;
    uint4 q = (node < N_NODES)
        ? *(const uint4*)(cv + (size_t)(g * N_NODES + node) * CAP + w * 4)
        : make_uint4(0, 0, 0, 0);
    *(uint4*)(&cvl[(g * 32 + i2) * CAPL + w * 4]) = q;
  }
  __syncthreads();
}

// ---------------- hop1 fused: both graphs gather x0h; k0 term; out = bias + x0@W0 ----------------
// grid = 2*RBLK_H: sid = bid/RBLK_H handles slices [sid*4, sid*4+4)
__global__ void __launch_bounds__(256, 4) k_hop1f(const int* __restrict__ cnt,
                                                  const u32* __restrict__ cv,
                                                  const u16* __restrict__ x0h,
                                                  const u16* __restrict__ wfrag,
                                                  const float* __restrict__ bias,
                                                  u16* __restrict__ slabA0,
                                                  u16* __restrict__ slabA1,
                                                  float* __restrict__ out) {
  __shared__ u32 cvl[2 * 32 * CAPL];
  __shared__ int nn[64];
  const int sid = blockIdx.x / RBLK_H;
  const int rbase = (blockIdx.x - sid * RBLK_H) * 32;
  stage_cv<2>(cnt, cv, rbase, cvl, nn);

  const int wid = threadIdx.x >> 6, lane = threadIdx.x & 63;
  const int gi = lane >> 3, pe = lane & 7;
  const int i2 = wid * 8 + gi;
  const int node = rbase + i2;
  const bool nv = node < N_NODES;
  const int n0 = nn[i2], n1 = nn[32 + i2];
  const int m0 = wave_max(n0), m1 = wave_max(n1);
  const u32* cvp0 = &cvl[i2 * CAPL];
  const u32* cvp1 = &cvl[(32 + i2) * CAPL];

  const int t = wid >> 1, obp = (wid & 1) * 2;
  const int ar = lane & 15, kg = lane >> 4, col = lane & 15;
  const int anode = min(rbase + t * 16 + ar, N_NODES - 1);
  const float bv0 = bias[obp * 16 + col];
  const float bv1 = bias[(obp + 1) * 16 + col];

  for (int s = sid * 4; s < sid * 4 + 4; ++s) {
    const u16* xb = x0h + s * SFEAT + pe * 8;
    float y0[8], y1[8];
    gather_lds(cvp0, xb, n0, m0, y0);
    gather_lds(cvp1, xb, n1, m1, y1);
    if (nv) {
      size_t doff = (size_t)node * BD + s * SFEAT + pe * 8;
      *(uint4*)(slabA0 + doff) = make_uint4(pack2(y0[0], y0[1]), pack2(y0[2], y0[3]),
                                            pack2(y0[4], y0[5]), pack2(y0[6], y0[7]));
      *(uint4*)(slabA1 + doff) = make_uint4(pack2(y1[0], y1[1]), pack2(y1[2], y1[3]),
                                            pack2(y1[4], y1[5]), pack2(y1[6], y1[7]));
    }
    f32x4 acc0 = {0.f, 0.f, 0.f, 0.f}, acc1 = {0.f, 0.f, 0.f, 0.f};
    #pragma unroll
    for (int h = 0; h < 2; ++h) {
      short8 a = *(const short8*)(x0h + (size_t)anode * BD + s * SFEAT + h * 32 + kg * 8);
      acc0 = __builtin_amdgcn_mfma_f32_16x16x32_bf16(a, *wfp(wfrag, 0, h, obp, lane), acc0, 0, 0, 0);
      acc1 = __builtin_amdgcn_mfma_f32_16x16x32_bf16(a, *wfp(wfrag, 0, h, obp + 1, lane), acc1, 0, 0, 0);
    }
    #pragma unroll
    for (int reg = 0; reg < 4; ++reg) {
      int onode = rbase + t * 16 + kg * 4 + reg;
      if (onode < N_NODES) {
        size_t ob_ = ((size_t)s * N_NODES + onode) * ODIM;
        out[ob_ + obp * 16 + col] = acc0[reg] + bv0;
        out[ob_ + (obp + 1) * 16 + col] = acc1[reg] + bv1;
      }
    }
  }
}

// ---------------- hop2: y = 2*(A@slab) - x0; out += slab@W_KSELF + y@W_KY ----------------
// grid = 2*RBLK_H: sid handles slices [sid*4, sid*4+4)
template<int KSELF, int KY>
__global__ void __launch_bounds__(256, 4) k_hop2(const int* __restrict__ cnt_g,
                                                 const u32* __restrict__ cv_g,
                                                 const u16* __restrict__ srcslab,
                                                 const u16* __restrict__ x0h,
                                                 const u16* __restrict__ wfrag,
                                                 float* __restrict__ out) {
  __shared__ u32 cvl[32 * CAPL];
  __shared__ int nn[32];
  __shared__ u16 ytile[32 * YSTR];
  const int sid = blockIdx.x / RBLK_H;
  const int rbase = (blockIdx.x - sid * RBLK_H) * 32;
  stage_cv<1>(cnt_g, cv_g, rbase, cvl, nn);

  const int wid = threadIdx.x >> 6, lane = threadIdx.x & 63;
  const int gi = lane >> 3, pe = lane & 7;
  const int i2 = wid * 8 + gi;
  const int node = rbase + i2;
  const int nsafe = min(node, N_NODES - 1);
  const int n = nn[i2];
  const int m = wave_max(n);
  const u32* cvp = &cvl[i2 * CAPL];

  const int t = wid >> 1, obp = (wid & 1) * 2;
  const int ar = lane & 15, kg = lane >> 4, col = lane & 15;
  const int anode = min(rbase + t * 16 + ar, N_NODES - 1);

  for (int s = sid * 4; s < sid * 4 + 4; ++s) {
    const u16* xb = srcslab + s * SFEAT + pe * 8;
    float y[8];
    gather_lds(cvp, xb, n, m, y);
    {
      uint4 qp = *(const uint4*)(x0h + (size_t)nsafe * BD + s * SFEAT + pe * 8);
      float p[8] = {bfl(qp.x), bfh(qp.x), bfl(qp.y), bfh(qp.y),
                    bfl(qp.z), bfh(qp.z), bfl(qp.w), bfh(qp.w)};
      #pragma unroll
      for (int j = 0; j < 8; ++j) y[j] = 2.f * y[j] - p[j];
    }
    *(uint4*)(&ytile[i2 * YSTR + pe * 8]) =
        make_uint4(pack2(y[0], y[1]), pack2(y[2], y[3]),
                   pack2(y[4], y[5]), pack2(y[6], y[7]));
    __syncthreads();
    f32x4 acc0 = {0.f, 0.f, 0.f, 0.f}, acc1 = {0.f, 0.f, 0.f, 0.f};
    #pragma unroll
    for (int h = 0; h < 2; ++h) {
      short8 aS = *(const short8*)(srcslab + (size_t)anode * BD + s * SFEAT + h * 32 + kg * 8);
      short8 aY = *(const short8*)(&ytile[(t * 16 + ar) * YSTR + h * 32 + kg * 8]);
      acc0 = __builtin_amdgcn_mfma_f32_16x16x32_bf16(aS, *wfp(wfrag, KSELF, h, obp, lane), acc0, 0, 0, 0);
      acc1 = __builtin_amdgcn_mfma_f32_16x16x32_bf16(aS, *wfp(wfrag, KSELF, h, obp + 1, lane), acc1, 0, 0, 0);
      acc0 = __builtin_amdgcn_mfma_f32_16x16x32_bf16(aY, *wfp(wfrag, KY, h, obp, lane), acc0, 0, 0, 0);
      acc1 = __builtin_amdgcn_mfma_f32_16x16x32_bf16(aY, *wfp(wfrag, KY, h, obp + 1, lane), acc1, 0, 0, 0);
    }
    #pragma unroll
    for (int reg = 0; reg < 4; ++reg) {
      int onode = rbase + t * 16 + kg * 4 + reg;
      if (onode < N_NODES) {
        size_t ob_ = ((size_t)s * N_NODES + onode) * ODIM;
        out[ob_ + obp * 16 + col] += acc0[reg];
        out[ob_ + (obp + 1) * 16 + col] += acc1[reg];
      }
    }
    __syncthreads();   // ytile reused next slice
  }
}

// ---------------- launcher ----------------
extern "C" void kernel_launch(void* const* d_in, const int* in_sizes, int n_in,
                              void* d_out, int out_size, void* d_ws, size_t ws_size,
                              hipStream_t stream) {
  const float* x      = (const float*)d_in[0];
  const int*   rows0  = (const int*)d_in[1];
  const int*   cols0  = (const int*)d_in[2];
  const float* vals0  = (const float*)d_in[3];
  const int*   rows1  = (const int*)d_in[4];
  const int*   cols1  = (const int*)d_in[5];
  const float* vals1  = (const float*)d_in[6];
  const float* weight = (const float*)d_in[7];
  const float* bias   = (const float*)d_in[8];
  float* out = (float*)d_out;
  const int E = in_sizes[1];
  const int E4 = E >> 2;

  char* p = (char*)d_ws;
  auto alloc = [&](size_t bytes) {
    char* q = p;
    p += (bytes + 255) & ~(size_t)255;
    return q;
  };
  u16* x0h    = (u16*)alloc((size_t)N_NODES * BD * sizeof(u16));        // 51.2 MB
  u16* slabA0 = (u16*)alloc((size_t)N_NODES * BD * sizeof(u16));        // 51.2 MB
  u16* slabA1 = (u16*)alloc((size_t)N_NODES * BD * sizeof(u16));        // 51.2 MB
  int* cnt    = (int*)alloc((size_t)2 * N_NODES * sizeof(int));         // 0.4 MB
  u32* cv     = (u32*)alloc((size_t)2 * N_NODES * CAP * sizeof(u32));   // 28.8 MB
  u16* wfrag  = (u16*)alloc((size_t)2560 * 8 * sizeof(u16));            // 40 KB
  if ((size_t)(p - (char*)d_ws) > ws_size) return;

  const int tot4 = BDIM * N_NODES * DDIM / 4;
  k_transpose_h<<<(tot4 + 255) / 256, 256, 0, stream>>>(x, x0h, tot4);

  (void)hipMemsetAsync(cnt, 0, (size_t)2 * N_NODES * sizeof(int), stream);
  const int bpc = (2 * E4 + 255) / 256;
  k_scatter_cap<<<SCHUNKS * bpc, 256, 0, stream>>>(rows0, cols0, vals0,
                                                   rows1, cols1, vals1,
                                                   cnt, cv, E4, bpc);
  k_prep_w<<<1, 256, 0, stream>>>(weight, wfrag);

  // hop 1 (both graphs) + k0 term; writes slabs + out
  k_hop1f<<<2 * RBLK_H, 256, 0, stream>>>(cnt, cv, x0h, wfrag, bias, slabA0, slabA1, out);
  // hop 2 graph 0: k1 (slabA0) + k2 (cheb) contributions
  k_hop2<1, 2><<<2 * RBLK_H, 256, 0, stream>>>(cnt, cv, slabA0, x0h, wfrag, out);
  // hop 2 graph 1: k3 (slabA1) + k4 (cheb) contributions
  k_hop2<3, 4><<<2 * RBLK_H, 256, 0, stream>>>(cnt + N_NODES, cv + (size_t)N_NODES * CAP,
                                               slabA1, x0h, wfrag, out);
}